// Round 3
// baseline (143.184 us; speedup 1.0000x reference)
//
#include <hip/hip_runtime.h>
#include <hip/hip_bf16.h>

// Chamfer loss, B=8, N=M=8192, D=3, fp32.
// result = (mean_n min_m d2(a_n,b_m) + mean_m min_n d2) / 2
// d2 = a2 + b2 - 2ab; track max_q where q = ab - 0.5*b2, then
// d2_min = max(a2 - 2*max_q, 0).
//
// R3: (a) chunk-major partial layout + float4 stores (R2 had 64MB of
// write-amplified HBM traffic from 4B/64B-stride stores); (b) IL=16 via
// 4 groups of 4 consecutive points per thread -> halves LDS-pipe pressure
// per VALU inst (was ~86% of the ds_read_b128 throughput budget).

#define BATCH   8
#define NPTS    8192
#define BLK     256
#define TOTAL_A (2 * BATCH * NPTS)    // 131072
#define P2_BLOCKS (TOTAL_A / BLK)     // 512

template <int NCH, int GROUPS>
__global__ __launch_bounds__(BLK) void chamfer_pass1_t(
    const float* __restrict__ pred, const float* __restrict__ gt,
    float* __restrict__ partial) {
  constexpr int CH  = NPTS / NCH;          // b-points per chunk
  constexpr int IL  = GROUPS * 4;          // a-points per thread
  constexpr int PPB = BLK * IL;            // a-points per block
  constexpr int NBv = NPTS / PPB;          // n-tiles

  __shared__ float4 bs[CH];

  const int bid   = blockIdx.x;
  const int chunk = bid & (NCH - 1);
  const int r     = bid / NCH;             // pow2 -> shift
  const int nb    = r & (NBv - 1);
  const int r2    = r / NBv;
  const int batch = r2 & (BATCH - 1);
  const int side  = r2 >> 3;

  const float* A  = (side == 0) ? pred : gt;
  const float* Bp = (side == 0) ? gt : pred;
  const int t = threadIdx.x;

  // stage b-chunk into LDS as (x, y, z, 0.5*|b|^2)
  const float* bbase = Bp + ((size_t)batch * NPTS + (size_t)chunk * CH) * 3;
  for (int p = t; p < CH; p += BLK) {
    float bx = bbase[p * 3 + 0];
    float by = bbase[p * 3 + 1];
    float bz = bbase[p * 3 + 2];
    bs[p] = make_float4(bx, by, bz, 0.5f * (bx * bx + by * by + bz * bz));
  }
  __syncthreads();

  // load IL a-points per thread: GROUPS groups of 4 consecutive points,
  // each group = 12 consecutive floats = 3 float4 loads (coalesced).
  float ax[IL], ay[IL], az[IL], mq[IL];
  const float* abase = A + ((size_t)batch * NPTS + (size_t)nb * PPB) * 3;
#pragma unroll
  for (int g = 0; g < GROUPS; g++) {
    const int n0 = g * (BLK * 4) + t * 4;
    const float4* a4 = (const float4*)(abase + (size_t)n0 * 3);
    float4 f0 = a4[0], f1 = a4[1], f2 = a4[2];
    ax[g*4+0] = f0.x; ay[g*4+0] = f0.y; az[g*4+0] = f0.z;
    ax[g*4+1] = f0.w; ay[g*4+1] = f1.x; az[g*4+1] = f1.y;
    ax[g*4+2] = f1.z; ay[g*4+2] = f1.w; az[g*4+2] = f2.x;
    ax[g*4+3] = f2.y; ay[g*4+3] = f2.z; az[g*4+3] = f2.w;
#pragma unroll
    for (int k = 0; k < 4; k++) mq[g*4+k] = -1e30f;
  }

  // main loop: 2 broadcast LDS reads + IL*(6 FMA + 1 max3) per step
#pragma unroll 2
  for (int j = 0; j < CH; j += 2) {
    float4 b0 = bs[j];
    float4 b1 = bs[j + 1];
#pragma unroll
    for (int i = 0; i < IL; i++) {
      float q0 = fmaf(ax[i], b0.x, fmaf(ay[i], b0.y, fmaf(az[i], b0.z, -b0.w)));
      float q1 = fmaf(ax[i], b1.x, fmaf(ay[i], b1.y, fmaf(az[i], b1.z, -b1.w)));
      mq[i] = fmaxf(fmaxf(q0, q1), mq[i]);   // -> v_max3_f32
    }
  }

  // chunk-major partial: partial[chunk*TOTAL_A + sb*NPTS + n], float4 stores
  const int sb = side * BATCH + batch;
  float* pb = partial + (size_t)chunk * TOTAL_A + (size_t)sb * NPTS + (size_t)nb * PPB;
#pragma unroll
  for (int g = 0; g < GROUPS; g++) {
    const int n0 = g * (BLK * 4) + t * 4;
    float4 v = make_float4(mq[g*4+0], mq[g*4+1], mq[g*4+2], mq[g*4+3]);
    *(float4*)(pb + n0) = v;
  }
}

template <int NCH>
__global__ __launch_bounds__(BLK) void chamfer_pass2_t(
    const float* __restrict__ pred, const float* __restrict__ gt,
    const float* __restrict__ partial, float* __restrict__ blockSums) {
  const int gid  = blockIdx.x * BLK + threadIdx.x;   // [0, TOTAL_A)
  const int side = gid >> 16;                        // BATCH*NPTS == 65536
  const int rem  = gid & 65535;                      // batch*NPTS + n

  const float* A = (side == 0) ? pred : gt;
  float x = A[(size_t)rem * 3 + 0];
  float y = A[(size_t)rem * 3 + 1];
  float z = A[(size_t)rem * 3 + 2];
  float a2 = fmaf(x, x, fmaf(y, y, z * z));

  float mq = -1e30f;
#pragma unroll
  for (int c = 0; c < NCH; c++) {
    mq = fmaxf(mq, partial[(size_t)c * TOTAL_A + gid]);   // coalesced
  }
  float d2 = fmaxf(fmaf(-2.0f, mq, a2), 0.0f);

  // block reduction: wave shuffle then LDS across 4 waves
  float v = d2;
  for (int off = 32; off > 0; off >>= 1) v += __shfl_down(v, off);
  __shared__ float wsum[BLK / 64];
  int lane = threadIdx.x & 63, wv = threadIdx.x >> 6;
  if (lane == 0) wsum[wv] = v;
  __syncthreads();
  if (wv == 0) {
    float s = (lane < (BLK / 64)) ? wsum[lane] : 0.0f;
    for (int off = 2; off > 0; off >>= 1) s += __shfl_down(s, off);
    if (lane == 0) blockSums[blockIdx.x] = s;
  }
}

__global__ __launch_bounds__(BLK) void chamfer_pass3(
    const float* __restrict__ blockSums, float* __restrict__ out) {
  const int t = threadIdx.x;
  float v = blockSums[t] + blockSums[t + BLK];   // 512 sums
  for (int off = 32; off > 0; off >>= 1) v += __shfl_down(v, off);
  __shared__ float wsum[BLK / 64];
  int lane = t & 63, wv = t >> 6;
  if (lane == 0) wsum[wv] = v;
  __syncthreads();
  if (t == 0) {
    float s = wsum[0] + wsum[1] + wsum[2] + wsum[3];
    out[0] = s * (1.0f / (float)TOTAL_A);   // (sum1+sum2)/(2*65536)
  }
}

extern "C" void kernel_launch(void* const* d_in, const int* in_sizes, int n_in,
                              void* d_out, int out_size, void* d_ws, size_t ws_size,
                              hipStream_t stream) {
  const float* pred = (const float*)d_in[0];
  const float* gt   = (const float*)d_in[1];
  float* out = (float*)d_out;
  float* partial = (float*)d_ws;

  const size_t need32 = (size_t)TOTAL_A * 32 * sizeof(float) + 4096;  // ~16.8 MB

  if (ws_size >= need32) {
    constexpr int NCH = 32, GROUPS = 4;            // IL=16, NB=2
    float* blockSums = partial + (size_t)TOTAL_A * NCH;
    const int p1_blocks = 2 * BATCH * (NPTS / (BLK * GROUPS * 4)) * NCH;  // 1024
    chamfer_pass1_t<NCH, GROUPS><<<p1_blocks, BLK, 0, stream>>>(pred, gt, partial);
    chamfer_pass2_t<NCH><<<P2_BLOCKS, BLK, 0, stream>>>(pred, gt, partial, blockSums);
    chamfer_pass3<<<1, BLK, 0, stream>>>(blockSums, out);
  } else {
    constexpr int NCH = 16, GROUPS = 2;            // IL=8, NB=4 (8 MB scratch)
    float* blockSums = partial + (size_t)TOTAL_A * NCH;
    const int p1_blocks = 2 * BATCH * (NPTS / (BLK * GROUPS * 4)) * NCH;  // 1024
    chamfer_pass1_t<NCH, GROUPS><<<p1_blocks, BLK, 0, stream>>>(pred, gt, partial);
    chamfer_pass2_t<NCH><<<P2_BLOCKS, BLK, 0, stream>>>(pred, gt, partial, blockSums);
    chamfer_pass3<<<1, BLK, 0, stream>>>(blockSums, out);
  }
}